// Round 20
// baseline (129.814 us; speedup 1.0000x reference)
//
#include <hip/hip_runtime.h>
#include <math.h>

#define N_PTS 131072
#define BSEG 64
#define CC 256
#define BM 64                    // rows per tile
#define NSTEP 8
#define EXP_SHIFT 4.0f

#define INV_SQRT_DH 0.17677669529663687f  // 1/sqrt(32)

typedef short v8s __attribute__((ext_vector_type(8)));
typedef float v4f __attribute__((ext_vector_type(4)));
typedef int   v4i __attribute__((ext_vector_type(4)));

__device__ __forceinline__ float bf2f(unsigned short h) {
    unsigned u = ((unsigned)h) << 16;
    return __builtin_bit_cast(float, u);
}

__device__ __forceinline__ unsigned short f2bf(float f) {
    unsigned u = __builtin_bit_cast(unsigned, f);
    u += 0x7fffu + ((u >> 16) & 1u);
    return (unsigned short)(u >> 16);
}

// pack 8 fp32 -> 8 bf16 (RNE)
__device__ __forceinline__ v8s pack8(const float* x) {
    int h2[4];
    #pragma unroll
    for (int i = 0; i < 4; ++i)
        h2[i] = (int)(((unsigned)f2bf(x[2 * i + 1]) << 16) | f2bf(x[2 * i]));
    return __builtin_bit_cast(v8s, make_int4(h2[0], h2[1], h2[2], h2[3]));
}

__device__ __forceinline__ v8s as_v8s(int4 v) { return __builtin_bit_cast(v8s, v); }

// ---------------------------------------------------------------------------
// prep: bx 0..63 -> kv proj row bx; bx 64..127 -> weight pack to
// W1[kf(32)][n(256)][8] single bf16 plane.
// ---------------------------------------------------------------------------
__global__ __launch_bounds__(256) void prep_kernel(
    const float* __restrict__ k, const float* __restrict__ v,
    const float* __restrict__ Wk, const float* __restrict__ bk,
    const float* __restrict__ Wv, const float* __restrict__ bv,
    const float* __restrict__ Wq, const float* __restrict__ Wo,
    float* __restrict__ kps, float* __restrict__ vp, float* __restrict__ ssum,
    short* __restrict__ W1q, short* __restrict__ W1o) {
    int bx = blockIdx.x;
    int c = threadIdx.x;
    if (bx < 64) {
        int b = bx;
        const float4* krow  = (const float4*)(k + (size_t)b * CC);
        const float4* vrow  = (const float4*)(v + (size_t)b * CC);
        const float4* wkrow = (const float4*)(Wk + (size_t)c * CC);
        const float4* wvrow = (const float4*)(Wv + (size_t)c * CC);
        float accK = 0.f, accV = 0.f;
        #pragma unroll 8
        for (int i = 0; i < CC / 4; ++i) {
            float4 kk = krow[i], wk = wkrow[i];
            accK += kk.x * wk.x + kk.y * wk.y + kk.z * wk.z + kk.w * wk.w;
            float4 vv = vrow[i], wv = wvrow[i];
            accV += vv.x * wv.x + vv.y * wv.y + vv.z * wv.z + vv.w * wv.w;
        }
        kps[b * CC + c] = (accK + bk[c]) * INV_SQRT_DH;
        vp[b * CC + c] = accV + bv[c];
        ssum[b * CC + c] = 0.f;
    } else {
        int wx = bx - 64;
        const float* W = (wx >= 32) ? Wo : Wq;
        short* W1 = (wx >= 32) ? W1o : W1q;
        int kf = wx & 31;
        const float* src = W + (size_t)c * CC + kf * 8;
        float4 x0 = *(const float4*)(src);
        float4 x1 = *(const float4*)(src + 4);
        float x[8] = {x0.x, x0.y, x0.z, x0.w, x1.x, x1.y, x1.z, x1.w};
        *(v8s*)&W1[((size_t)kf * 256 + c) * 8] = pack8(x);
    }
}

// ---------------------------------------------------------------------------
// wo_scale: Wos[b][kf][n][8] = bf16( Wo[n][kf*8+e] * vp[b]/ssum[b] )
// grid = 64 segs * 32 kf = 2048 blocks x 256 threads (n).
// ---------------------------------------------------------------------------
__global__ __launch_bounds__(256) void wo_scale_kernel(
    const short* __restrict__ W1o, const float* __restrict__ vp,
    const float* __restrict__ ssum, short* __restrict__ Wos) {
    int b = blockIdx.x >> 5;
    int kf = blockIdx.x & 31;
    int n = threadIdx.x;
    const float* vpp = vp + (size_t)b * CC + kf * 8;
    const float* ssp = ssum + (size_t)b * CC + kf * 8;
    v4f a0 = *(const v4f*)vpp;
    v4f a1 = *(const v4f*)(vpp + 4);
    v4f s0 = *(const v4f*)ssp;
    v4f s1 = *(const v4f*)(ssp + 4);
    v8s w = *(const v8s*)&W1o[((size_t)kf * 256 + n) * 8];
    float x[8];
    #pragma unroll
    for (int e = 0; e < 4; ++e) {
        x[e]     = bf2f((unsigned short)w[e]) * __fdividef(a0[e], s0[e]);
        x[4 + e] = bf2f((unsigned short)w[4 + e]) * __fdividef(a1[e], s1[e]);
    }
    *(v8s*)&Wos[(size_t)b * 65536 + ((size_t)kf * 256 + n) * 8] = pack8(x);
}

// ---------------------------------------------------------------------------
// One BM=64 tile of the single-plane bf16 GEMM.
//  MODE 0: A=q fp32 (nontemporal) -> bf16 LDS. p = exp((acc+bq)*kps-4) ->
//          bf16 p (plain stores, L3-resident); ssum atomics.
//  MODE 1: A=p bf16, per-row transform x = p*vp/ssum at staging (slow tiles).
//  MODE 2: A=p bf16 RAW via global_load_lds (pre-swizzled global source,
//          linear LDS dest); B = per-segment pre-scaled Wos (fast tiles).
//  MODE 1/2 epilogue: out = acc + bo (nontemporal f32).
// ---------------------------------------------------------------------------
template <int MODE>
__device__ __forceinline__ void gemm_tile(
    char* lds, const int m0,
    const void* __restrict__ Ain, const short* __restrict__ W1,
    const float* __restrict__ bias, void* __restrict__ Outv,
    const int* __restrict__ batch, const float* __restrict__ kps,
    const float* __restrict__ vp, const float* __restrict__ ssum_ro,
    float* __restrict__ ssum) {

    const int tid = threadIdx.x;
    const int lane = tid & 63;
    const int wn = tid >> 6;         // 0..7: 32-col strip
    const int kfl = lane >> 4;       // k-chunk 0..3
    const int rl = lane & 15;        // row (A) / col (B) in fragment
    const int colb = wn * 32;
    const int hsw = ((rl & 7) << 2) | (rl >> 3);

    // ---- stage A tile ----
    if (MODE == 2) {
        // raw bf16 p -> LDS via global_load_lds; source pre-swizzled so the
        // linear LDS fill lands in the swizzled layout the K-loop reads.
        #pragma unroll
        for (int r = 0; r < 4; ++r) {
            int row0 = r * 16 + wn * 2;          // wave-uniform 2-row group
            int row = row0 + (lane >> 5);
            int h = ((row & 7) << 2) | ((row >> 3) & 1);
            int g16 = (lane & 31) ^ h;
            const unsigned short* g = (const unsigned short*)Ain +
                (size_t)(m0 + row) * CC + g16 * 8;
            __builtin_amdgcn_global_load_lds(
                (const __attribute__((address_space(1))) void*)g,
                (__attribute__((address_space(3))) void*)(lds + row0 * 512),
                16, 0, 0);
        }
    } else {
        #pragma unroll
        for (int i = 0; i < 4; ++i) {
            int j = i * 512 + tid;           // 0..2047
            int row = j >> 5;                // 0..63
            int ch = j & 31;                 // 16B chunk (8 cols)
            int h = ((row & 7) << 2) | ((row >> 3) & 1);
            int off = row * 512 + ((ch ^ h) << 4);
            if (MODE == 0) {
                const v4f* ap = (const v4f*)((const float*)Ain +
                    (size_t)(m0 + row) * CC + ch * 8);
                v4f x0 = __builtin_nontemporal_load(ap);
                v4f x1 = __builtin_nontemporal_load(ap + 1);
                float x[8] = {x0.x, x0.y, x0.z, x0.w, x1.x, x1.y, x1.z, x1.w};
                *(v8s*)(lds + off) = pack8(x);
            } else {
                const v4i* ap = (const v4i*)((const unsigned short*)Ain +
                    (size_t)(m0 + row) * CC + ch * 8);
                v4i praw = *ap;              // plain load: p is L3-resident
                v8s p = __builtin_bit_cast(v8s, praw);
                int b = batch[m0 + row];
                const float* vpp = vp + (size_t)b * CC + ch * 8;
                const float* ssp = ssum_ro + (size_t)b * CC + ch * 8;
                v4f a0 = *(const v4f*)vpp;
                v4f a1 = *(const v4f*)(vpp + 4);
                v4f s0 = *(const v4f*)ssp;
                v4f s1 = *(const v4f*)(ssp + 4);
                float x[8];
                #pragma unroll
                for (int e = 0; e < 4; ++e) {
                    x[e]     = bf2f((unsigned short)p[e]) * __fdividef(a0[e], s0[e]);
                    x[4 + e] = bf2f((unsigned short)p[4 + e]) * __fdividef(a1[e], s1[e]);
                }
                *(v8s*)(lds + off) = pack8(x);
            }
        }
    }

    v4f acc[4][2];
    #pragma unroll
    for (int i = 0; i < 4; ++i)
        #pragma unroll
        for (int j = 0; j < 2; ++j) acc[i][j] = (v4f){0.f, 0.f, 0.f, 0.f};

    // prefetch B for s=0 (single plane: 2 x v8s = 8 VGPR)
    v8s bcur[2];
    #pragma unroll
    for (int ni = 0; ni < 2; ++ni)
        bcur[ni] = as_v8s(*(const int4*)(W1 +
            ((size_t)kfl * 256 + colb + ni * 16 + rl) * 8));

    __syncthreads();   // barrier A: tile staged (drains global_load_lds too)

    #pragma unroll
    for (int s = 0; s < NSTEP; ++s) {
        v8s bnx[2];
        if (s + 1 < NSTEP) {
            #pragma unroll
            for (int ni = 0; ni < 2; ++ni)
                bnx[ni] = as_v8s(*(const int4*)(W1 +
                    ((size_t)((s + 1) * 4 + kfl) * 256 + colb + ni * 16 + rl) * 8));
        }
        #pragma unroll
        for (int mi = 0; mi < 4; ++mi) {
            int abase = (mi * 16 + rl) * 512 + (((s * 4 + kfl) ^ hsw) << 4);
            v8s a = *(const v8s*)(lds + abase);
            #pragma unroll
            for (int ni = 0; ni < 2; ++ni)
                acc[mi][ni] = __builtin_amdgcn_mfma_f32_16x16x32_bf16(
                    a, bcur[ni], acc[mi][ni], 0, 0, 0);
        }
        #pragma unroll
        for (int ni = 0; ni < 2; ++ni) bcur[ni] = bnx[ni];
    }

    __syncthreads();   // barrier B: A-LDS dead -> reuse as bounce

    const float bb0 = bias[colb + rl];
    const float bb1 = bias[colb + 16 + rl];

    if (MODE == 0) {
        unsigned short* Ou = (unsigned short*)Outv;
        const int bseg = batch[m0];
        const bool fastT = (bseg == batch[m0 + BM - 1]);
        if (!fastT) {
            int curb = -1;
            float r0 = 0.f, r1 = 0.f;
            #pragma unroll
            for (int mi = 0; mi < 4; ++mi)
                #pragma unroll
                for (int r4 = 0; r4 < 4; ++r4) {
                    int row = m0 + mi * 16 + kfl * 4 + r4;
                    int b = batch[row];
                    if (b != curb) {
                        if (curb >= 0) {
                            atomicAdd(&ssum[(size_t)curb * CC + colb + rl], r0);
                            atomicAdd(&ssum[(size_t)curb * CC + colb + 16 + rl], r1);
                            r0 = r1 = 0.f;
                        }
                        curb = b;
                    }
                    float k0 = kps[(size_t)b * CC + colb + rl];
                    float k1 = kps[(size_t)b * CC + colb + 16 + rl];
                    float p0 = __expf((acc[mi][0][r4] + bb0) * k0 - EXP_SHIFT);
                    float p1 = __expf((acc[mi][1][r4] + bb1) * k1 - EXP_SHIFT);
                    Ou[(size_t)row * CC + colb + rl] = f2bf(p0);
                    Ou[(size_t)row * CC + colb + 16 + rl] = f2bf(p1);
                    r0 += p0; r1 += p1;
                }
            atomicAdd(&ssum[(size_t)curb * CC + colb + rl], r0);
            atomicAdd(&ssum[(size_t)curb * CC + colb + 16 + rl], r1);
        } else {
            float k0 = kps[(size_t)bseg * CC + colb + rl];
            float k1 = kps[(size_t)bseg * CC + colb + 16 + rl];
            float cs0 = 0.f, cs1 = 0.f;
            unsigned short* lwu = (unsigned short*)lds + wn * 1024;  // 2KB region
            #pragma unroll
            for (int mi = 0; mi < 4; ++mi) {
                #pragma unroll
                for (int r4 = 0; r4 < 4; ++r4) {
                    float p0 = __expf((acc[mi][0][r4] + bb0) * k0 - EXP_SHIFT);
                    float p1 = __expf((acc[mi][1][r4] + bb1) * k1 - EXP_SHIFT);
                    cs0 += p0; cs1 += p1;
                    lwu[(kfl * 4 + r4) * 40 + rl] = f2bf(p0);
                    lwu[(kfl * 4 + r4) * 40 + 16 + rl] = f2bf(p1);
                }
                asm volatile("s_waitcnt lgkmcnt(0)" ::: "memory");
                int row16 = lane >> 2, chunk = lane & 3;
                v4i pv = *(const v4i*)&lwu[row16 * 40 + chunk * 8];
                *(v4i*)&Ou[(size_t)(m0 + mi * 16 + row16) * CC + colb + chunk * 8] = pv;
                asm volatile("s_waitcnt lgkmcnt(0)" ::: "memory");
            }
            cs0 += __shfl_xor(cs0, 16); cs0 += __shfl_xor(cs0, 32);
            cs1 += __shfl_xor(cs1, 16); cs1 += __shfl_xor(cs1, 32);
            if (kfl == 0) {
                atomicAdd(&ssum[(size_t)bseg * CC + colb + rl], cs0);
                atomicAdd(&ssum[(size_t)bseg * CC + colb + 16 + rl], cs1);
            }
        }
    } else {
        float* Of = (float*)Outv;
        float* lwf = (float*)(lds + wn * 2048);   // 2KB region: 8 rows x 36 f
        #pragma unroll
        for (int mi = 0; mi < 4; ++mi)
            #pragma unroll
            for (int c = 0; c < 2; ++c) {
                if ((kfl >> 1) == c) {
                    #pragma unroll
                    for (int r4 = 0; r4 < 4; ++r4) {
                        lwf[((kfl & 1) * 4 + r4) * 36 + rl] = acc[mi][0][r4] + bb0;
                        lwf[((kfl & 1) * 4 + r4) * 36 + 16 + rl] = acc[mi][1][r4] + bb1;
                    }
                }
                asm volatile("s_waitcnt lgkmcnt(0)" ::: "memory");
                int r = lane >> 3, c4 = lane & 7;
                v4f pv = *(const v4f*)&lwf[r * 36 + c4 * 4];
                __builtin_nontemporal_store(pv,
                    (v4f*)&Of[(size_t)(m0 + mi * 16 + c * 8 + r) * CC + colb + c4 * 4]);
                asm volatile("s_waitcnt lgkmcnt(0)" ::: "memory");
            }
    }
}

// ---------------------------------------------------------------------------
__global__ __launch_bounds__(512, 4) void gemm_k0(
    const float* __restrict__ q, const short* __restrict__ W1,
    const float* __restrict__ bias, unsigned short* __restrict__ attn,
    const int* __restrict__ batch, const float* __restrict__ kps,
    float* __restrict__ ssum) {
    __shared__ char lds[32768];
    gemm_tile<0>(lds, blockIdx.x * BM, (const void*)q, W1, bias,
                 (void*)attn, batch, kps, nullptr, nullptr, ssum);
}

__global__ __launch_bounds__(512, 4) void gemm_k1(
    const unsigned short* __restrict__ attn, const short* __restrict__ W1o,
    const short* __restrict__ Wos, const float* __restrict__ bias,
    float* __restrict__ out, const int* __restrict__ batch,
    const float* __restrict__ vp, const float* __restrict__ ssum) {
    __shared__ char lds[32768];
    const int m0 = blockIdx.x * BM;
    const int bseg = batch[m0];
    if (bseg == batch[m0 + BM - 1]) {
        gemm_tile<2>(lds, m0, (const void*)attn, Wos + (size_t)bseg * 65536,
                     bias, (void*)out, batch, nullptr, nullptr, nullptr, nullptr);
    } else {
        gemm_tile<1>(lds, m0, (const void*)attn, W1o, bias,
                     (void*)out, batch, nullptr, vp, ssum, nullptr);
    }
}

// ---------------------------------------------------------------------------
extern "C" void kernel_launch(void* const* d_in, const int* in_sizes, int n_in,
                              void* d_out, int out_size, void* d_ws, size_t ws_size,
                              hipStream_t stream) {
    const float* q  = (const float*)d_in[0];
    const float* k  = (const float*)d_in[1];
    const float* v  = (const float*)d_in[2];
    const int* batch = (const int*)d_in[3];
    const float* Wq = (const float*)d_in[4];
    const float* bq = (const float*)d_in[5];
    const float* Wk = (const float*)d_in[6];
    const float* bk = (const float*)d_in[7];
    const float* Wv = (const float*)d_in[8];
    const float* bv = (const float*)d_in[9];
    const float* Wo = (const float*)d_in[10];
    const float* bo = (const float*)d_in[11];
    float* out = (float*)d_out;

    char* wsp = (char*)d_ws;
    unsigned short* attn = (unsigned short*)wsp;
    wsp += (size_t)N_PTS * CC * sizeof(unsigned short);                          // 67 MB
    float* kps  = (float*)wsp;  wsp += (size_t)BSEG * CC * sizeof(float);
    float* vp   = (float*)wsp;  wsp += (size_t)BSEG * CC * sizeof(float);
    float* ssum = (float*)wsp;  wsp += (size_t)BSEG * CC * sizeof(float);
    short* W1q  = (short*)wsp;  wsp += (size_t)32 * 256 * 8 * sizeof(short);     // 128 KB
    short* W1o  = (short*)wsp;  wsp += (size_t)32 * 256 * 8 * sizeof(short);
    short* Wos  = (short*)wsp;  wsp += (size_t)BSEG * 65536 * sizeof(short);     // 8.4 MB

    prep_kernel<<<128, 256, 0, stream>>>(k, v, Wk, bk, Wv, bv, Wq, Wo,
                                         kps, vp, ssum, W1q, W1o);
    gemm_k0<<<N_PTS / BM, 512, 0, stream>>>(q, W1q, bq, attn, batch, kps, ssum);
    wo_scale_kernel<<<BSEG * 32, 256, 0, stream>>>(W1o, vp, ssum, Wos);
    gemm_k1<<<N_PTS / BM, 512, 0, stream>>>(attn, W1o, Wos, bo, out, batch, vp, ssum);
}

// Round 21
// 117.661 us; speedup vs baseline: 1.1033x; 1.1033x over previous
//
#include <hip/hip_runtime.h>
#include <math.h>

#define N_PTS 131072
#define BSEG 64
#define CC 256
#define BM 64                    // rows per tile
#define NSTEP 8
#define EXP_SHIFT 4.0f

#define INV_SQRT_DH 0.17677669529663687f  // 1/sqrt(32)

typedef short v8s __attribute__((ext_vector_type(8)));
typedef float v4f __attribute__((ext_vector_type(4)));
typedef int   v4i __attribute__((ext_vector_type(4)));

__device__ __forceinline__ float bf2f(unsigned short h) {
    unsigned u = ((unsigned)h) << 16;
    return __builtin_bit_cast(float, u);
}

__device__ __forceinline__ unsigned short f2bf(float f) {
    unsigned u = __builtin_bit_cast(unsigned, f);
    u += 0x7fffu + ((u >> 16) & 1u);
    return (unsigned short)(u >> 16);
}

// pack 8 fp32 -> 8 bf16 (RNE)
__device__ __forceinline__ v8s pack8(const float* x) {
    int h2[4];
    #pragma unroll
    for (int i = 0; i < 4; ++i)
        h2[i] = (int)(((unsigned)f2bf(x[2 * i + 1]) << 16) | f2bf(x[2 * i]));
    return __builtin_bit_cast(v8s, make_int4(h2[0], h2[1], h2[2], h2[3]));
}

__device__ __forceinline__ v8s as_v8s(int4 v) { return __builtin_bit_cast(v8s, v); }

// ---------------------------------------------------------------------------
// prep: bx 0..63 -> kv proj row bx; bx 64..127 -> weight pack to
// W1[kf(32)][n(256)][8] single bf16 plane.
// ---------------------------------------------------------------------------
__global__ __launch_bounds__(256) void prep_kernel(
    const float* __restrict__ k, const float* __restrict__ v,
    const float* __restrict__ Wk, const float* __restrict__ bk,
    const float* __restrict__ Wv, const float* __restrict__ bv,
    const float* __restrict__ Wq, const float* __restrict__ Wo,
    float* __restrict__ kps, float* __restrict__ vp, float* __restrict__ ssum,
    short* __restrict__ W1q, short* __restrict__ W1o) {
    int bx = blockIdx.x;
    int c = threadIdx.x;
    if (bx < 64) {
        int b = bx;
        const float4* krow  = (const float4*)(k + (size_t)b * CC);
        const float4* vrow  = (const float4*)(v + (size_t)b * CC);
        const float4* wkrow = (const float4*)(Wk + (size_t)c * CC);
        const float4* wvrow = (const float4*)(Wv + (size_t)c * CC);
        float accK = 0.f, accV = 0.f;
        #pragma unroll 8
        for (int i = 0; i < CC / 4; ++i) {
            float4 kk = krow[i], wk = wkrow[i];
            accK += kk.x * wk.x + kk.y * wk.y + kk.z * wk.z + kk.w * wk.w;
            float4 vv = vrow[i], wv = wvrow[i];
            accV += vv.x * wv.x + vv.y * wv.y + vv.z * wv.z + vv.w * wv.w;
        }
        kps[b * CC + c] = (accK + bk[c]) * INV_SQRT_DH;
        vp[b * CC + c] = accV + bv[c];
        ssum[b * CC + c] = 0.f;
    } else {
        int wx = bx - 64;
        const float* W = (wx >= 32) ? Wo : Wq;
        short* W1 = (wx >= 32) ? W1o : W1q;
        int kf = wx & 31;
        const float* src = W + (size_t)c * CC + kf * 8;
        float4 x0 = *(const float4*)(src);
        float4 x1 = *(const float4*)(src + 4);
        float x[8] = {x0.x, x0.y, x0.z, x0.w, x1.x, x1.y, x1.z, x1.w};
        *(v8s*)&W1[((size_t)kf * 256 + c) * 8] = pack8(x);
    }
}

// ---------------------------------------------------------------------------
// One BM=64 tile of the single-plane bf16 GEMM (R15/R19 proven structure).
//  MODE 0: A=q fp32 (nontemporal) -> bf16 LDS. Epilogue: p = exp((acc+bq)*
//          kps-4) -> bf16 p (PLAIN stores: keep L3-resident); ssum atomics.
//  MODE 1: A=p bf16 (plain loads, L3-hit), transform x = p*vp/ssum at
//          staging (sv merged in). Epilogue: out = acc + bo (nontemporal).
// ---------------------------------------------------------------------------
template <int MODE>
__device__ __forceinline__ void gemm_tile(
    char* lds, const int m0,
    const void* __restrict__ Ain, const short* __restrict__ W1,
    const float* __restrict__ bias, void* __restrict__ Outv,
    const int* __restrict__ batch, const float* __restrict__ kps,
    const float* __restrict__ vp, const float* __restrict__ ssum_ro,
    float* __restrict__ ssum) {

    const int tid = threadIdx.x;
    const int lane = tid & 63;
    const int wn = tid >> 6;         // 0..7: 32-col strip
    const int kfl = lane >> 4;       // k-chunk 0..3
    const int rl = lane & 15;        // row (A) / col (B) in fragment
    const int colb = wn * 32;
    const int hsw = ((rl & 7) << 2) | (rl >> 3);

    // ---- stage A tile: 4 items of 8 elements per thread, swizzled ----
    #pragma unroll
    for (int i = 0; i < 4; ++i) {
        int j = i * 512 + tid;           // 0..2047
        int row = j >> 5;                // 0..63
        int ch = j & 31;                 // 16B chunk (8 cols)
        int h = ((row & 7) << 2) | ((row >> 3) & 1);
        int off = row * 512 + ((ch ^ h) << 4);
        if (MODE == 0) {
            const v4f* ap = (const v4f*)((const float*)Ain +
                (size_t)(m0 + row) * CC + ch * 8);
            v4f x0 = __builtin_nontemporal_load(ap);
            v4f x1 = __builtin_nontemporal_load(ap + 1);
            float x[8] = {x0.x, x0.y, x0.z, x0.w, x1.x, x1.y, x1.z, x1.w};
            *(v8s*)(lds + off) = pack8(x);
        } else {
            const v4i* ap = (const v4i*)((const unsigned short*)Ain +
                (size_t)(m0 + row) * CC + ch * 8);
            v4i praw = *ap;              // plain load: p is L3-resident
            v8s p = __builtin_bit_cast(v8s, praw);
            int b = batch[m0 + row];
            const float* vpp = vp + (size_t)b * CC + ch * 8;
            const float* ssp = ssum_ro + (size_t)b * CC + ch * 8;
            v4f a0 = *(const v4f*)vpp;
            v4f a1 = *(const v4f*)(vpp + 4);
            v4f s0 = *(const v4f*)ssp;
            v4f s1 = *(const v4f*)(ssp + 4);
            float x[8];
            #pragma unroll
            for (int e = 0; e < 4; ++e) {
                x[e]     = bf2f((unsigned short)p[e]) * __fdividef(a0[e], s0[e]);
                x[4 + e] = bf2f((unsigned short)p[4 + e]) * __fdividef(a1[e], s1[e]);
            }
            *(v8s*)(lds + off) = pack8(x);
        }
    }

    v4f acc[4][2];
    #pragma unroll
    for (int i = 0; i < 4; ++i)
        #pragma unroll
        for (int j = 0; j < 2; ++j) acc[i][j] = (v4f){0.f, 0.f, 0.f, 0.f};

    // prefetch B for s=0 (single plane: 2 x v8s = 8 VGPR)
    v8s bcur[2];
    #pragma unroll
    for (int ni = 0; ni < 2; ++ni)
        bcur[ni] = as_v8s(*(const int4*)(W1 +
            ((size_t)kfl * 256 + colb + ni * 16 + rl) * 8));

    __syncthreads();   // barrier A: tile staged

    #pragma unroll
    for (int s = 0; s < NSTEP; ++s) {
        v8s bnx[2];
        if (s + 1 < NSTEP) {
            #pragma unroll
            for (int ni = 0; ni < 2; ++ni)
                bnx[ni] = as_v8s(*(const int4*)(W1 +
                    ((size_t)((s + 1) * 4 + kfl) * 256 + colb + ni * 16 + rl) * 8));
        }
        #pragma unroll
        for (int mi = 0; mi < 4; ++mi) {
            int abase = (mi * 16 + rl) * 512 + (((s * 4 + kfl) ^ hsw) << 4);
            v8s a = *(const v8s*)(lds + abase);
            #pragma unroll
            for (int ni = 0; ni < 2; ++ni)
                acc[mi][ni] = __builtin_amdgcn_mfma_f32_16x16x32_bf16(
                    a, bcur[ni], acc[mi][ni], 0, 0, 0);
        }
        #pragma unroll
        for (int ni = 0; ni < 2; ++ni) bcur[ni] = bnx[ni];
    }

    __syncthreads();   // barrier B: A-LDS dead -> reuse as bounce

    const float bb0 = bias[colb + rl];
    const float bb1 = bias[colb + 16 + rl];

    if (MODE == 0) {
        unsigned short* Ou = (unsigned short*)Outv;
        const int bseg = batch[m0];
        const bool fastT = (bseg == batch[m0 + BM - 1]);
        if (!fastT) {
            // slow path: segment boundary inside tile (rare)
            int curb = -1;
            float r0 = 0.f, r1 = 0.f;
            #pragma unroll
            for (int mi = 0; mi < 4; ++mi)
                #pragma unroll
                for (int r4 = 0; r4 < 4; ++r4) {
                    int row = m0 + mi * 16 + kfl * 4 + r4;
                    int b = batch[row];
                    if (b != curb) {
                        if (curb >= 0) {
                            atomicAdd(&ssum[(size_t)curb * CC + colb + rl], r0);
                            atomicAdd(&ssum[(size_t)curb * CC + colb + 16 + rl], r1);
                            r0 = r1 = 0.f;
                        }
                        curb = b;
                    }
                    float k0 = kps[(size_t)b * CC + colb + rl];
                    float k1 = kps[(size_t)b * CC + colb + 16 + rl];
                    float p0 = __expf((acc[mi][0][r4] + bb0) * k0 - EXP_SHIFT);
                    float p1 = __expf((acc[mi][1][r4] + bb1) * k1 - EXP_SHIFT);
                    Ou[(size_t)row * CC + colb + rl] = f2bf(p0);
                    Ou[(size_t)row * CC + colb + 16 + rl] = f2bf(p1);
                    r0 += p0; r1 += p1;
                }
            atomicAdd(&ssum[(size_t)curb * CC + colb + rl], r0);
            atomicAdd(&ssum[(size_t)curb * CC + colb + 16 + rl], r1);
        } else {
            float k0 = kps[(size_t)bseg * CC + colb + rl];
            float k1 = kps[(size_t)bseg * CC + colb + 16 + rl];
            float cs0 = 0.f, cs1 = 0.f;
            unsigned short* lwu = (unsigned short*)lds + wn * 1024;  // 2KB region
            #pragma unroll
            for (int mi = 0; mi < 4; ++mi) {
                #pragma unroll
                for (int r4 = 0; r4 < 4; ++r4) {
                    float p0 = __expf((acc[mi][0][r4] + bb0) * k0 - EXP_SHIFT);
                    float p1 = __expf((acc[mi][1][r4] + bb1) * k1 - EXP_SHIFT);
                    cs0 += p0; cs1 += p1;
                    lwu[(kfl * 4 + r4) * 40 + rl] = f2bf(p0);
                    lwu[(kfl * 4 + r4) * 40 + 16 + rl] = f2bf(p1);
                }
                asm volatile("s_waitcnt lgkmcnt(0)" ::: "memory");
                int row16 = lane >> 2, chunk = lane & 3;
                v4i pv = *(const v4i*)&lwu[row16 * 40 + chunk * 8];
                *(v4i*)&Ou[(size_t)(m0 + mi * 16 + row16) * CC + colb + chunk * 8] = pv;
                asm volatile("s_waitcnt lgkmcnt(0)" ::: "memory");
            }
            cs0 += __shfl_xor(cs0, 16); cs0 += __shfl_xor(cs0, 32);
            cs1 += __shfl_xor(cs1, 16); cs1 += __shfl_xor(cs1, 32);
            if (kfl == 0) {
                atomicAdd(&ssum[(size_t)bseg * CC + colb + rl], cs0);
                atomicAdd(&ssum[(size_t)bseg * CC + colb + 16 + rl], cs1);
            }
        }
    } else {
        float* Of = (float*)Outv;
        float* lwf = (float*)(lds + wn * 2048);   // 2KB region: 8 rows x 36 f
        #pragma unroll
        for (int mi = 0; mi < 4; ++mi)
            #pragma unroll
            for (int c = 0; c < 2; ++c) {
                if ((kfl >> 1) == c) {
                    #pragma unroll
                    for (int r4 = 0; r4 < 4; ++r4) {
                        lwf[((kfl & 1) * 4 + r4) * 36 + rl] = acc[mi][0][r4] + bb0;
                        lwf[((kfl & 1) * 4 + r4) * 36 + 16 + rl] = acc[mi][1][r4] + bb1;
                    }
                }
                asm volatile("s_waitcnt lgkmcnt(0)" ::: "memory");
                int r = lane >> 3, c4 = lane & 7;
                v4f pv = *(const v4f*)&lwf[r * 36 + c4 * 4];
                __builtin_nontemporal_store(pv,
                    (v4f*)&Of[(size_t)(m0 + mi * 16 + c * 8 + r) * CC + colb + c4 * 4]);
                asm volatile("s_waitcnt lgkmcnt(0)" ::: "memory");
            }
    }
}

// ---------------------------------------------------------------------------
__global__ __launch_bounds__(512, 4) void gemm_k0(
    const float* __restrict__ q, const short* __restrict__ W1,
    const float* __restrict__ bias, unsigned short* __restrict__ attn,
    const int* __restrict__ batch, const float* __restrict__ kps,
    float* __restrict__ ssum) {
    __shared__ char lds[32768];
    gemm_tile<0>(lds, blockIdx.x * BM, (const void*)q, W1, bias,
                 (void*)attn, batch, kps, nullptr, nullptr, ssum);
}

__global__ __launch_bounds__(512, 4) void gemm_k1(
    const unsigned short* __restrict__ attn, const short* __restrict__ W1,
    const float* __restrict__ bias, float* __restrict__ out,
    const int* __restrict__ batch, const float* __restrict__ vp,
    const float* __restrict__ ssum) {
    __shared__ char lds[32768];
    gemm_tile<1>(lds, blockIdx.x * BM, (const void*)attn, W1, bias,
                 (void*)out, batch, nullptr, vp, ssum, nullptr);
}

// ---------------------------------------------------------------------------
extern "C" void kernel_launch(void* const* d_in, const int* in_sizes, int n_in,
                              void* d_out, int out_size, void* d_ws, size_t ws_size,
                              hipStream_t stream) {
    const float* q  = (const float*)d_in[0];
    const float* k  = (const float*)d_in[1];
    const float* v  = (const float*)d_in[2];
    const int* batch = (const int*)d_in[3];
    const float* Wq = (const float*)d_in[4];
    const float* bq = (const float*)d_in[5];
    const float* Wk = (const float*)d_in[6];
    const float* bk = (const float*)d_in[7];
    const float* Wv = (const float*)d_in[8];
    const float* bv = (const float*)d_in[9];
    const float* Wo = (const float*)d_in[10];
    const float* bo = (const float*)d_in[11];
    float* out = (float*)d_out;

    char* wsp = (char*)d_ws;
    unsigned short* attn = (unsigned short*)wsp;
    wsp += (size_t)N_PTS * CC * sizeof(unsigned short);                          // 67 MB
    float* kps  = (float*)wsp;  wsp += (size_t)BSEG * CC * sizeof(float);
    float* vp   = (float*)wsp;  wsp += (size_t)BSEG * CC * sizeof(float);
    float* ssum = (float*)wsp;  wsp += (size_t)BSEG * CC * sizeof(float);
    short* W1q  = (short*)wsp;  wsp += (size_t)32 * 256 * 8 * sizeof(short);     // 128 KB
    short* W1o  = (short*)wsp;  wsp += (size_t)32 * 256 * 8 * sizeof(short);

    prep_kernel<<<128, 256, 0, stream>>>(k, v, Wk, bk, Wv, bv, Wq, Wo,
                                         kps, vp, ssum, W1q, W1o);
    gemm_k0<<<N_PTS / BM, 512, 0, stream>>>(q, W1q, bq, attn, batch, kps, ssum);
    gemm_k1<<<N_PTS / BM, 512, 0, stream>>>(attn, W1o, bo, out, batch, vp, ssum);
}